// Round 5
// baseline (1859.612 us; speedup 1.0000x reference)
//
#include <hip/hip_runtime.h>
#include <hip/hip_bf16.h>

// Problem constants (fixed by setup_inputs)
#define MDIM 8192    // B*S = 4*2048
#define KDIM 4096
#define NDIM 11008   // O
#define GDIM 32      // K/128 groups

// ---- 256x256x64 GEMM geometry ----
#define BM 256
#define BN 256
#define BK 64
#define NKT (KDIM / BK)      // 64 K-tiles
#define MT (MDIM / BM)       // 32
#define NT (NDIM / BN)       // 43
#define NWG (MT * NT)        // 1376 blocks (divisible by 8 -> XCD swizzle bijective)
#define CPX (NWG / 8)        // 172 blocks per XCD

typedef __attribute__((ext_vector_type(8))) short short8;
typedef __attribute__((ext_vector_type(4))) float f32x4;
typedef __attribute__((address_space(3))) unsigned char lds_u8;

__device__ __forceinline__ unsigned short f2bf(float f) {
    unsigned int u = __float_as_uint(f);
    u += 0x7FFFu + ((u >> 16) & 1u);   // round-to-nearest-even (inputs finite)
    return (unsigned short)(u >> 16);
}

__device__ __forceinline__ void async_ld16(const void* g, lds_u8* l) {
    __builtin_amdgcn_global_load_lds(
        (const __attribute__((address_space(1))) void*)g,
        (__attribute__((address_space(3))) void*)l, 16, 0, 0);
}

// stage one half-tile (128 rows x 64 cols bf16 = 16 KiB): 2 x global_load_lds / thread
__device__ __forceinline__ void stage_half(const unsigned short* src, lds_u8* dst) {
    async_ld16(src, dst);                             // rows  0..63  of the half
    async_ld16(src + (size_t)64 * KDIM, dst + 8192);  // rows 64..127
}

#define BAR()   __builtin_amdgcn_s_barrier()
#define FENCE() asm volatile("" ::: "memory")
#define VMW(n)  asm volatile("s_waitcnt vmcnt(" #n ")" ::: "memory")
#define SP1()   __builtin_amdgcn_s_setprio(1)
#define SP0()   __builtin_amdgcn_s_setprio(0)

// load A fragments FB..FB+3 (both K=32 slices) from swizzled LDS
template<int FB>
__device__ __forceinline__ void ldA4(short8 (&a)[4][2],
                                     const unsigned short* p0,
                                     const unsigned short* p1) {
#pragma unroll
    for (int f = 0; f < 4; ++f) {
        a[f][0] = *(const short8*)(p0 + (FB + f) * 1024);
        a[f][1] = *(const short8*)(p1 + (FB + f) * 1024);
    }
}

// load B fragment pair NB..NB+1 (both K=32 slices) into a 2-frag array
template<int NB>
__device__ __forceinline__ void ldB2(short8 (&bb)[2][2],
                                     const unsigned short* p0,
                                     const unsigned short* p1) {
#pragma unroll
    for (int n = 0; n < 2; ++n) {
        bb[n][0] = *(const short8*)(p0 + (NB + n) * 1024);
        bb[n][1] = *(const short8*)(p1 + (NB + n) * 1024);
    }
}

// one C-quadrant x K=64: 16 MFMA (ks outer -> consecutive MFMAs independent)
template<int FB, int NB>
__device__ __forceinline__ void mm16(f32x4 (&acc)[8][4],
                                     const short8 (&a)[4][2],
                                     const short8 (&bb)[2][2]) {
#pragma unroll
    for (int ks = 0; ks < 2; ++ks)
#pragma unroll
        for (int f = 0; f < 4; ++f)
#pragma unroll
            for (int n = 0; n < 2; ++n)
                acc[FB + f][NB + n] = __builtin_amdgcn_mfma_f32_16x16x32_bf16(
                    a[f][ks], bb[n][ks], acc[FB + f][NB + n], 0, 0, 0);
}

// ---------------- Fused prepass: x fp32->bf16  AND  w int8*scale->bf16 ----------------
#define XBLOCKS ((MDIM * (size_t)KDIM) / 8 / 256)           // 16384
#define WBLOCKS ((NDIM * (size_t)KDIM) / 8 / 256)           // 22016
__global__ __launch_bounds__(256) void prep_kernel(const float* __restrict__ x,
                                                   const int* __restrict__ w,
                                                   const float* __restrict__ sc,
                                                   unsigned short* __restrict__ xb,
                                                   unsigned short* __restrict__ wb) {
    size_t b = blockIdx.x;
    if (b < XBLOCKS) {
        size_t i = (b * 256 + threadIdx.x) * 8;
        float4 f0 = *(const float4*)(x + i);
        float4 f1 = *(const float4*)(x + i + 4);
        union { unsigned short u[8]; uint4 v; } p;
        p.u[0] = f2bf(f0.x); p.u[1] = f2bf(f0.y); p.u[2] = f2bf(f0.z); p.u[3] = f2bf(f0.w);
        p.u[4] = f2bf(f1.x); p.u[5] = f2bf(f1.y); p.u[6] = f2bf(f1.z); p.u[7] = f2bf(f1.w);
        *(uint4*)(xb + i) = p.v;
    } else {
        size_t base = ((b - XBLOCKS) * 256 + threadIdx.x) * 8;  // 8 consecutive k, one group
        int o = (int)(base >> 12);             // /4096
        int k = (int)(base & 4095);
        float s = sc[o * GDIM + (k >> 7)];
        int4 w0 = *(const int4*)(w + base);
        int4 w1 = *(const int4*)(w + base + 4);
        union { unsigned short u[8]; uint4 v; } p;
        p.u[0] = f2bf((float)w0.x * s); p.u[1] = f2bf((float)w0.y * s);
        p.u[2] = f2bf((float)w0.z * s); p.u[3] = f2bf((float)w0.w * s);
        p.u[4] = f2bf((float)w1.x * s); p.u[5] = f2bf((float)w1.y * s);
        p.u[6] = f2bf((float)w1.z * s); p.u[7] = f2bf((float)w1.w * s);
        *(uint4*)(wb + base) = p.v;
    }
}

// ---------------- GEMM: C[M][N] = A[M][K] * B[N][K]^T, 256^2, 2-barrier/K-tile,
//                  ASYMMETRIC wave roles (wave-level software pipelining) ----
// 512 threads = 8 waves (2M x 4N). Waves 0-3 (wm=0) and 4-7 (wm=1) pair up per SIMD.
// G0 keeps the round-4 split schedule; G1 front-loads all 20 ds_reads and runs its
// 64 MFMAs in one stream before barrier #1. Opposite phases on each SIMD -> one
// wave's ds_read window hides under the other's MFMA stream (m114 overlap), breaking
// the measured port+MFMA serialization (4647 = 2304 + 2368 cyc/tile).
// Invariants kept per-wave: staging issue order (A(kt+1) at top, B(kt+2) after BAR1),
// VMW(4) drains the 8 oldest of 12 (= B(kt+1)+A(kt+1)), both barriers hit once/tile.
__global__ __launch_bounds__(512, 2) void gemm256(const unsigned short* __restrict__ A,
                                                  const unsigned short* __restrict__ B,
                                                  float* __restrict__ C) {
    __shared__ unsigned short lds[65536];   // 128 KiB

    const int tid  = threadIdx.x;
    const int wave = tid >> 6;
    const int lane = tid & 63;
    const int wm = wave >> 2, wn = wave & 3;
    const int q  = lane >> 4;          // k-quad within K=32 slice
    const int ml = lane & 15;          // m (A) / n (B) index within 16-tile
    const int s  = ml & 7;             // read-side swizzle term (= row&7)

    // ---- block swizzle: XCD-contiguous chunks, M-fastest within XCD ----
    const int p    = blockIdx.x;
    const int tix  = (p & 7) * CPX + (p >> 3);
    const int bm   = tix & 31;
    const int bn   = tix >> 5;
    const int row0 = bm * BM, col0 = bn * BN;

    // ---- ds_read bases (ushort elements) ----
    const int e0  = ((q    ) ^ s) * 8;             // ks=0 chunk, swizzled
    const int e1  = ((4 + q) ^ s) * 8;             // ks=1 chunk, swizzled
    const int rdA = wm * 8192 + ml * 64;
    const int rdB = 32768 + wn * 4096 + ml * 64;

    // ---- staging mapping: thread t -> row t>>3, phys 16B-slot t&7 ----
    const int rA = tid >> 3;                        // 0..63
    const int cS = (tid & 7) ^ (rA & 7);            // logical slot held at phys slot
    const unsigned short* gA = A + (size_t)(row0 + rA) * KDIM + cS * 8;
    const unsigned short* gB = B + (size_t)(col0 + rA) * KDIM + cS * 8;
    lds_u8* L8A = (lds_u8*)lds + tid * 16;          // A region byte base + my chunk
    lds_u8* L8B = L8A + 65536;                      // B region

    // ---- prologue: tile0 (A,B -> buf0) + tile1 (B -> buf1) ----
    stage_half(gA,                      L8A);
    stage_half(gA + (size_t)128 * KDIM, L8A + 16384);
    stage_half(gB,                      L8B);
    stage_half(gB + (size_t)128 * KDIM, L8B + 16384);
    stage_half(gB + 64,                      L8B + 32768);
    stage_half(gB + (size_t)128 * KDIM + 64, L8B + 32768 + 16384);
    const unsigned short* pAg = gA + 64;     // A source for tile kt+1
    const unsigned short* pBg = gB + 128;    // B source for tile kt+2
    VMW(4);                                  // tile0 complete; tile1 B in flight
    BAR(); FENCE();

    short8 a[4][2], a4[4][2], b1[2][2], b2[2][2];
    f32x4 acc[8][4];
    const f32x4 z = {0.f, 0.f, 0.f, 0.f};
#pragma unroll
    for (int f = 0; f < 8; ++f)
#pragma unroll
        for (int n = 0; n < 4; ++n) acc[f][n] = z;

    // pre-read tile0's b01 (buf0)
    ldB2<0>(b1, lds + rdB + e0, lds + rdB + e1);

    for (int kt = 0; kt < NKT; ++kt) {
        const int cur = kt & 1;
        const unsigned short* Lc  = lds + cur * 16384;
        const unsigned short* pA0 = Lc + rdA + e0;
        const unsigned short* pA1 = Lc + rdA + e1;
        const unsigned short* pB0 = Lc + rdB + e0;
        const unsigned short* pB1 = Lc + rdB + e1;
        const unsigned short* Ln  = lds + (cur ^ 1) * 16384;   // next tile's buffer
        const unsigned short* pB0n = Ln + rdB + e0;
        const unsigned short* pB1n = Ln + rdB + e1;
        lds_u8* dA = L8A + (((kt + 1) & 1) << 15);   // A dest buffer (kt+1)
        lds_u8* dB = L8B + ((cur) << 15);            // B dest buffer (kt+2 == kt mod 2)
        const bool stA = (kt + 1 < NKT);
        const bool stB = (kt + 2 < NKT);

        if (wm == 0) {
            // ===== G0: round-4 split schedule (reads interleaved mid-tile) =====
            ldA4<0>(a, pA0, pA1);                              // 8 rd
            if (stA) {
                stage_half(pAg, dA);
                stage_half(pAg + (size_t)128 * KDIM, dA + 16384);
            }
            SP1(); mm16<0, 0>(acc, a, b1); SP0();              // C1
            ldB2<2>(b2, pB0, pB1);                             // 4 rd
            SP1(); mm16<0, 2>(acc, a, b2); SP0();              // C2
            ldA4<4>(a, pA0, pA1);                              // 8 rd (reuse a[]; drains under BAR)

            BAR(); FENCE();    // join #1: B(kt) region free

            if (stB) {
                stage_half(pBg, dB);
                stage_half(pBg + (size_t)128 * KDIM, dB + 16384);
            }
            SP1(); mm16<4, 0>(acc, a, b1); SP0();              // C3

            if (stB)      { VMW(4); }
            else if (stA) { VMW(0); }
            BAR(); FENCE();    // join #2: tile kt+1 published

            if (stA) ldB2<0>(b1, pB0n, pB1n);                  // preread b01(kt+1)
            SP1(); mm16<4, 2>(acc, a, b2); SP0();              // C4
        } else {
            // ===== G1: front-load ALL reads, one 64-MFMA stream before BAR1 =====
            ldA4<0>(a,  pA0, pA1);                             // 8 rd
            ldA4<4>(a4, pA0, pA1);                             // 8 rd
            ldB2<2>(b2, pB0, pB1);                             // 4 rd
            if (stA) {
                stage_half(pAg, dA);
                stage_half(pAg + (size_t)128 * KDIM, dA + 16384);
            }
            SP1();
            mm16<0, 0>(acc, a,  b1);                           // C1
            mm16<0, 2>(acc, a,  b2);                           // C2
            mm16<4, 0>(acc, a4, b1);                           // C3
            mm16<4, 2>(acc, a4, b2);                           // C4
            SP0();

            BAR(); FENCE();    // join #1

            if (stB) {
                stage_half(pBg, dB);
                stage_half(pBg + (size_t)128 * KDIM, dB + 16384);
            }
            if (stB)      { VMW(4); }
            else if (stA) { VMW(0); }
            BAR(); FENCE();    // join #2

            if (stA) ldB2<0>(b1, pB0n, pB1n);                  // preread b01(kt+1)
        }

        pAg += 64; pBg += 64;
    }

    // ---- epilogue: C/D layout col=lane&15, row=(lane>>4)*4+reg ----
#pragma unroll
    for (int f = 0; f < 8; ++f) {
        const int r0 = row0 + wm * 128 + f * 16 + q * 4;
#pragma unroll
        for (int n = 0; n < 4; ++n) {
            const int c = col0 + wn * 64 + n * 16 + ml;
            float* Cp = C + (size_t)r0 * NDIM + c;
#pragma unroll
            for (int r = 0; r < 4; ++r) Cp[(size_t)r * NDIM] = acc[f][n][r];
        }
    }
}

// ---------------- Fallback (only if ws too small): naive fp32 ----------------
__global__ __launch_bounds__(256) void gemm_fallback(const float* __restrict__ X,
                                                     const int* __restrict__ W,
                                                     const float* __restrict__ S,
                                                     float* __restrict__ C) {
    int n = blockIdx.x * 256 + threadIdx.x;
    int m = blockIdx.y;
    if (n >= NDIM) return;
    const float* xr = X + (size_t)m * KDIM;
    const int*   wr = W + (size_t)n * KDIM;
    float acc = 0.f;
    for (int g = 0; g < GDIM; ++g) {
        float s = S[n * GDIM + g];
        float part = 0.f;
        for (int k = 0; k < 128; ++k)
            part += xr[g * 128 + k] * (float)wr[g * 128 + k];
        acc += part * s;
    }
    C[(size_t)m * NDIM + n] = acc;
}

extern "C" void kernel_launch(void* const* d_in, const int* in_sizes, int n_in,
                              void* d_out, int out_size, void* d_ws, size_t ws_size,
                              hipStream_t stream) {
    const float* x  = (const float*)d_in[0];
    const int*   w  = (const int*)d_in[1];
    const float* sc = (const float*)d_in[2];
    float* out = (float*)d_out;

    const size_t bytesA = (size_t)MDIM * KDIM * 2;   // 64 MiB bf16 x
    const size_t bytesB = (size_t)NDIM * KDIM * 2;   // 86 MiB bf16 dequant w

    if (ws_size >= bytesA + bytesB) {
        unsigned short* Abf = (unsigned short*)d_ws;
        unsigned short* Bbf = (unsigned short*)((char*)d_ws + bytesA);

        prep_kernel<<<(unsigned)(XBLOCKS + WBLOCKS), 256, 0, stream>>>(x, w, sc, Abf, Bbf);
        gemm256<<<NWG, 512, 0, stream>>>(Abf, Bbf, out);
    } else {
        dim3 grid((NDIM + 255) / 256, MDIM);
        gemm_fallback<<<grid, 256, 0, stream>>>(x, w, sc, out);
    }
}

// Round 6
// 1159.483 us; speedup vs baseline: 1.6038x; 1.6038x over previous
//
#include <hip/hip_runtime.h>
#include <hip/hip_bf16.h>

// Problem constants (fixed by setup_inputs)
#define MDIM 8192    // B*S = 4*2048
#define KDIM 4096
#define NDIM 11008   // O
#define GDIM 32      // K/128 groups

// ---- 256x256x64 GEMM geometry ----
#define BM 256
#define BN 256
#define BK 64
#define NKT (KDIM / BK)      // 64 K-tiles
#define MT (MDIM / BM)       // 32
#define NT (NDIM / BN)       // 43
#define NWG (MT * NT)        // 1376 blocks (divisible by 8 -> XCD swizzle bijective)
#define CPX (NWG / 8)        // 172 blocks per XCD

typedef __attribute__((ext_vector_type(8))) short short8;
typedef __attribute__((ext_vector_type(4))) float f32x4;
typedef __attribute__((address_space(3))) unsigned char lds_u8;

__device__ __forceinline__ unsigned short f2bf(float f) {
    unsigned int u = __float_as_uint(f);
    u += 0x7FFFu + ((u >> 16) & 1u);   // round-to-nearest-even (inputs finite)
    return (unsigned short)(u >> 16);
}

__device__ __forceinline__ void async_ld16(const void* g, lds_u8* l) {
    __builtin_amdgcn_global_load_lds(
        (const __attribute__((address_space(1))) void*)g,
        (__attribute__((address_space(3))) void*)l, 16, 0, 0);
}

// stage one half-tile (128 rows x 64 cols bf16 = 16 KiB): 2 x global_load_lds / thread
__device__ __forceinline__ void stage_half(const unsigned short* src, lds_u8* dst) {
    async_ld16(src, dst);                             // rows  0..63  of the half
    async_ld16(src + (size_t)64 * KDIM, dst + 8192);  // rows 64..127
}

#define BAR()   __builtin_amdgcn_s_barrier()
#define FENCE() asm volatile("" ::: "memory")
#define VMW(n)  asm volatile("s_waitcnt vmcnt(" #n ")" ::: "memory")

// load A fragments FB..FB+3 (both K=32 slices) from swizzled LDS
template<int FB>
__device__ __forceinline__ void ldA4(short8 (&a)[4][2],
                                     const unsigned short* p0,
                                     const unsigned short* p1) {
#pragma unroll
    for (int f = 0; f < 4; ++f) {
        a[f][0] = *(const short8*)(p0 + (FB + f) * 1024);
        a[f][1] = *(const short8*)(p1 + (FB + f) * 1024);
    }
}

// load B fragment pair NB..NB+1 (both K=32 slices) into a 2-frag array
template<int NB>
__device__ __forceinline__ void ldB2(short8 (&bb)[2][2],
                                     const unsigned short* p0,
                                     const unsigned short* p1) {
#pragma unroll
    for (int n = 0; n < 2; ++n) {
        bb[n][0] = *(const short8*)(p0 + (NB + n) * 1024);
        bb[n][1] = *(const short8*)(p1 + (NB + n) * 1024);
    }
}

// one C-quadrant x K=64: 16 MFMA (ks outer -> consecutive MFMAs independent)
template<int FB, int NB>
__device__ __forceinline__ void mm16(f32x4 (&acc)[8][4],
                                     const short8 (&a)[4][2],
                                     const short8 (&bb)[2][2]) {
#pragma unroll
    for (int ks = 0; ks < 2; ++ks)
#pragma unroll
        for (int f = 0; f < 4; ++f)
#pragma unroll
            for (int n = 0; n < 2; ++n)
                acc[FB + f][NB + n] = __builtin_amdgcn_mfma_f32_16x16x32_bf16(
                    a[f][ks], bb[n][ks], acc[FB + f][NB + n], 0, 0, 0);
}

// ---------------- Fused prepass: x fp32->bf16  AND  w int8*scale->bf16 ----------------
#define XBLOCKS ((MDIM * (size_t)KDIM) / 8 / 256)           // 16384
#define WBLOCKS ((NDIM * (size_t)KDIM) / 8 / 256)           // 22016
__global__ __launch_bounds__(256) void prep_kernel(const float* __restrict__ x,
                                                   const int* __restrict__ w,
                                                   const float* __restrict__ sc,
                                                   unsigned short* __restrict__ xb,
                                                   unsigned short* __restrict__ wb) {
    size_t b = blockIdx.x;
    if (b < XBLOCKS) {
        size_t i = (b * 256 + threadIdx.x) * 8;
        float4 f0 = *(const float4*)(x + i);
        float4 f1 = *(const float4*)(x + i + 4);
        union { unsigned short u[8]; uint4 v; } p;
        p.u[0] = f2bf(f0.x); p.u[1] = f2bf(f0.y); p.u[2] = f2bf(f0.z); p.u[3] = f2bf(f0.w);
        p.u[4] = f2bf(f1.x); p.u[5] = f2bf(f1.y); p.u[6] = f2bf(f1.z); p.u[7] = f2bf(f1.w);
        *(uint4*)(xb + i) = p.v;
    } else {
        size_t base = ((b - XBLOCKS) * 256 + threadIdx.x) * 8;  // 8 consecutive k, one group
        int o = (int)(base >> 12);             // /4096
        int k = (int)(base & 4095);
        float s = sc[o * GDIM + (k >> 7)];
        int4 w0 = *(const int4*)(w + base);
        int4 w1 = *(const int4*)(w + base + 4);
        union { unsigned short u[8]; uint4 v; } p;
        p.u[0] = f2bf((float)w0.x * s); p.u[1] = f2bf((float)w0.y * s);
        p.u[2] = f2bf((float)w0.z * s); p.u[3] = f2bf((float)w0.w * s);
        p.u[4] = f2bf((float)w1.x * s); p.u[5] = f2bf((float)w1.y * s);
        p.u[6] = f2bf((float)w1.z * s); p.u[7] = f2bf((float)w1.w * s);
        *(uint4*)(wb + base) = p.v;
    }
}

// ---------------- GEMM: C[M][N] = A[M][K] * B[N][K]^T, 256^2 tile, 2-barrier/K-tile ----
// 512 threads = 8 waves (2M x 4N); per-wave output 128x64 = acc[8][4] f32x4.
// LDS 128 KiB: A[2 buf][16384e] at elem 0, B[2 buf][16384e] at elem 32768.
// 16x16x32 MFMA + 3-bit 16B-chunk XOR swizzle (measured conflict-free).
// 2 barriers per K-tile (round-4 skeleton). NO setprio: with 2 waves/SIMD, a
// prio-1 MFMA cluster starves the sibling wave's ds_read ISSUE, serializing
// port and MFMA pipe (m190: setprio hurts drift-style GEMM). b23 reads hoisted
// above C1 so the port keeps draining under the first MFMA cluster (compiler
// gates C1 on lgkmcnt(4): a03 done, b23 in flight).
__global__ __launch_bounds__(512, 2) void gemm256(const unsigned short* __restrict__ A,
                                                  const unsigned short* __restrict__ B,
                                                  float* __restrict__ C) {
    __shared__ unsigned short lds[65536];   // 128 KiB

    const int tid  = threadIdx.x;
    const int wave = tid >> 6;
    const int lane = tid & 63;
    const int wm = wave >> 2, wn = wave & 3;
    const int q  = lane >> 4;          // k-quad within K=32 slice
    const int ml = lane & 15;          // m (A) / n (B) index within 16-tile
    const int s  = ml & 7;             // read-side swizzle term (= row&7)

    // ---- block swizzle: XCD-contiguous chunks, M-fastest within XCD ----
    const int p    = blockIdx.x;
    const int tix  = (p & 7) * CPX + (p >> 3);
    const int bm   = tix & 31;
    const int bn   = tix >> 5;
    const int row0 = bm * BM, col0 = bn * BN;

    // ---- ds_read bases (ushort elements) ----
    const int e0  = ((q    ) ^ s) * 8;             // ks=0 chunk, swizzled
    const int e1  = ((4 + q) ^ s) * 8;             // ks=1 chunk, swizzled
    const int rdA = wm * 8192 + ml * 64;
    const int rdB = 32768 + wn * 4096 + ml * 64;

    // ---- staging mapping: thread t -> row t>>3, phys 16B-slot t&7 ----
    const int rA = tid >> 3;                        // 0..63
    const int cS = (tid & 7) ^ (rA & 7);            // logical slot held at phys slot
    const unsigned short* gA = A + (size_t)(row0 + rA) * KDIM + cS * 8;
    const unsigned short* gB = B + (size_t)(col0 + rA) * KDIM + cS * 8;
    lds_u8* L8A = (lds_u8*)lds + tid * 16;          // A region byte base + my chunk
    lds_u8* L8B = L8A + 65536;                      // B region

    // ---- prologue: tile0 (A,B -> buf0) + tile1 (B -> buf1) ----
    stage_half(gA,                      L8A);
    stage_half(gA + (size_t)128 * KDIM, L8A + 16384);
    stage_half(gB,                      L8B);
    stage_half(gB + (size_t)128 * KDIM, L8B + 16384);
    stage_half(gB + 64,                      L8B + 32768);
    stage_half(gB + (size_t)128 * KDIM + 64, L8B + 32768 + 16384);
    const unsigned short* pAg = gA + 64;     // A source for tile kt+1
    const unsigned short* pBg = gB + 128;    // B source for tile kt+2
    VMW(4);                                  // tile0 complete; tile1 B in flight
    BAR(); FENCE();

    short8 a[4][2], b1[2][2], b2[2][2];
    f32x4 acc[8][4];
    const f32x4 z = {0.f, 0.f, 0.f, 0.f};
#pragma unroll
    for (int f = 0; f < 8; ++f)
#pragma unroll
        for (int n = 0; n < 4; ++n) acc[f][n] = z;

    // pre-read tile0's b01 (buf0)
    ldB2<0>(b1, lds + rdB + e0, lds + rdB + e1);

    for (int kt = 0; kt < NKT; ++kt) {
        const int cur = kt & 1;
        const unsigned short* Lc  = lds + cur * 16384;
        const unsigned short* pA0 = Lc + rdA + e0;
        const unsigned short* pA1 = Lc + rdA + e1;
        const unsigned short* pB0 = Lc + rdB + e0;
        const unsigned short* pB1 = Lc + rdB + e1;
        const unsigned short* Ln  = lds + (cur ^ 1) * 16384;   // next tile's buffer
        const unsigned short* pB0n = Ln + rdB + e0;
        const unsigned short* pB1n = Ln + rdB + e1;
        lds_u8* dA = L8A + (((kt + 1) & 1) << 15);   // A dest buffer (kt+1)
        lds_u8* dB = L8B + ((cur) << 15);            // B dest buffer (kt+2 == kt mod 2)
        const bool stA = (kt + 1 < NKT);
        const bool stB = (kt + 2 < NKT);

        // ---- top: a03 reads (8) + b23 reads (4) | stage A(kt+1) both halves ----
        ldA4<0>(a, pA0, pA1);
        if (stA) {
            stage_half(pAg, dA);
            stage_half(pAg + (size_t)128 * KDIM, dA + 16384);
        }
        ldB2<2>(b2, pB0, pB1);     // queued behind a03; drains under C1

        // C1: a03 x b01 (compiler gates on a03 only -> lgkmcnt(4))
        mm16<0, 0>(acc, a, b1);

        // C2: a03 x b23 (lgkmcnt(0))
        mm16<0, 2>(acc, a, b2);

        // a47 reads (8, reuse a[]) issued BEFORE the join barrier -> drain under it
        ldA4<4>(a, pA0, pA1);

        BAR(); FENCE();    // join #1: all waves consumed b01/b23 -> B(kt) region free

        if (stB) {
            stage_half(pBg, dB);                               // B(kt+2) half0
            stage_half(pBg + (size_t)128 * KDIM, dB + 16384);  // B(kt+2) half1
        }

        // C3: a47 x b01
        mm16<4, 0>(acc, a, b1);

        if (stB)      { VMW(4); }   // drain B(kt+1)+A(kt+1) (8 oldest of 12); B(kt+2) in flight
        else if (stA) { VMW(0); }   // kt == NKT-2: only 8 outstanding, drain all
        BAR(); FENCE();             // join #2: tile kt+1 fully published

        if (stA) ldB2<0>(b1, pB0n, pB1n);   // pre-read b01(kt+1); hides under C4

        // C4: a47 x b23
        mm16<4, 2>(acc, a, b2);

        pAg += 64; pBg += 64;
    }

    // ---- epilogue: C/D layout col=lane&15, row=(lane>>4)*4+reg ----
#pragma unroll
    for (int f = 0; f < 8; ++f) {
        const int r0 = row0 + wm * 128 + f * 16 + q * 4;
#pragma unroll
        for (int n = 0; n < 4; ++n) {
            const int c = col0 + wn * 64 + n * 16 + ml;
            float* Cp = C + (size_t)r0 * NDIM + c;
#pragma unroll
            for (int r = 0; r < 4; ++r) Cp[(size_t)r * NDIM] = acc[f][n][r];
        }
    }
}

// ---------------- Fallback (only if ws too small): naive fp32 ----------------
__global__ __launch_bounds__(256) void gemm_fallback(const float* __restrict__ X,
                                                     const int* __restrict__ W,
                                                     const float* __restrict__ S,
                                                     float* __restrict__ C) {
    int n = blockIdx.x * 256 + threadIdx.x;
    int m = blockIdx.y;
    if (n >= NDIM) return;
    const float* xr = X + (size_t)m * KDIM;
    const int*   wr = W + (size_t)n * KDIM;
    float acc = 0.f;
    for (int g = 0; g < GDIM; ++g) {
        float s = S[n * GDIM + g];
        float part = 0.f;
        for (int k = 0; k < 128; ++k)
            part += xr[g * 128 + k] * (float)wr[g * 128 + k];
        acc += part * s;
    }
    C[(size_t)m * NDIM + n] = acc;
}

extern "C" void kernel_launch(void* const* d_in, const int* in_sizes, int n_in,
                              void* d_out, int out_size, void* d_ws, size_t ws_size,
                              hipStream_t stream) {
    const float* x  = (const float*)d_in[0];
    const int*   w  = (const int*)d_in[1];
    const float* sc = (const float*)d_in[2];
    float* out = (float*)d_out;

    const size_t bytesA = (size_t)MDIM * KDIM * 2;   // 64 MiB bf16 x
    const size_t bytesB = (size_t)NDIM * KDIM * 2;   // 86 MiB bf16 dequant w

    if (ws_size >= bytesA + bytesB) {
        unsigned short* Abf = (unsigned short*)d_ws;
        unsigned short* Bbf = (unsigned short*)((char*)d_ws + bytesA);

        prep_kernel<<<(unsigned)(XBLOCKS + WBLOCKS), 256, 0, stream>>>(x, w, sc, Abf, Bbf);
        gemm256<<<NWG, 512, 0, stream>>>(Abf, Bbf, out);
    } else {
        dim3 grid((NDIM + 255) / 256, MDIM);
        gemm_fallback<<<grid, 256, 0, stream>>>(x, w, sc, out);
    }
}